// Round 1
// baseline (152.134 us; speedup 1.0000x reference)
//
#include <hip/hip_runtime.h>
#include <hip/hip_bf16.h>
#include <stdint.h>

// Problem constants (from reference): B=32, N=2048, L=32768, D_IN=4, D=64
#define B_ 32
#define N_ 2048
#define L_ 32768

// Workspace layout (bytes):
//   [0, 2560)            : Wc1(4x64 f32) | Wc2(4x64 f32) | bc1(64 f32) | bc2(64 f32)
//   [4096, 4096+8MiB)    : g1 bf16 (B,N,64)  -- node_feat @ W1[:64]  + b_embed@W1_top + b1
//   [4096+8MiB, +16MiB)  : g2 bf16 (B,N,64)  -- node_feat @ W1[64:]  + b_embed@W1_bot
// Total ~16.8 MB.

static __device__ __forceinline__ unsigned f2bf(float f) {
    unsigned u = __float_as_uint(f);
    u += 0x7fffu + ((u >> 16) & 1u);   // round-to-nearest-even
    return u >> 16;
}

// ---------------- Kernel A: fold linears into 4x64 combos ----------------
__global__ void prep_kernel(const float* __restrict__ W_embed,
                            const float* __restrict__ b_embed,
                            const float* __restrict__ W1,
                            const float* __restrict__ b1,
                            float* __restrict__ wc) {
    int d = threadIdx.x;  // 0..63
    float acc1[4] = {0.f, 0.f, 0.f, 0.f};
    float acc2[4] = {0.f, 0.f, 0.f, 0.f};
    float bb1 = 0.f, bb2 = 0.f;
    for (int k = 0; k < 64; ++k) {
        float w1a = W1[k * 64 + d];          // W1_top column d
        float w1b = W1[(64 + k) * 64 + d];   // W1_bot column d
        float be = b_embed[k];
        bb1 = fmaf(be, w1a, bb1);
        bb2 = fmaf(be, w1b, bb2);
#pragma unroll
        for (int i = 0; i < 4; ++i) {
            float we = W_embed[i * 64 + k];
            acc1[i] = fmaf(we, w1a, acc1[i]);
            acc2[i] = fmaf(we, w1b, acc2[i]);
        }
    }
#pragma unroll
    for (int i = 0; i < 4; ++i) {
        wc[i * 64 + d] = acc1[i];
        wc[256 + i * 64 + d] = acc2[i];
    }
    wc[512 + d] = bb1 + b1[d];  // fold b1 into the src half
    wc[576 + d] = bb2;
}

// ---------------- Kernel B: per-node g1/g2 (bf16) ----------------
// 32 threads per node (each thread -> 2 features), 8 nodes per 256-thread block.
// Block->batch swizzle keeps batch b on XCD b%8 (matches edge kernel) so the
// bf16 g rows are produced in the L2 that will gather them.
__global__ __launch_bounds__(256) void node_kernel(
    const float4* __restrict__ pred_node,  // (B*N) float4 rows
    const float* __restrict__ wc,
    unsigned* __restrict__ g1, unsigned* __restrict__ g2) {
    int bid = blockIdx.x;        // 0..8191
    int x = bid & 7;             // XCD (heuristic: dispatch round-robin)
    int i = bid >> 3;            // 0..1023
    int b = x + 8 * (i >> 8);    // batch: 4 batches per XCD
    int chunk = i & 255;         // 256 chunks of 8 nodes
    int tid = threadIdx.x;
    int nsub = tid >> 5;         // node within block
    int dp = tid & 31;           // feature pair index (d0 = 2*dp)
    int node = b * N_ + chunk * 8 + nsub;

    float4 p = pred_node[node];

    const float2* wc1 = (const float2*)wc;          // 4 rows x 32 float2
    const float2* wc2 = (const float2*)(wc + 256);
    const float2* bc1 = (const float2*)(wc + 512);
    const float2* bc2 = (const float2*)(wc + 576);
    float2 c0 = wc1[dp], c1 = wc1[32 + dp], c2 = wc1[64 + dp], c3 = wc1[96 + dp];
    float2 e0 = wc2[dp], e1 = wc2[32 + dp], e2 = wc2[64 + dp], e3 = wc2[96 + dp];
    float2 bA = bc1[dp], bB = bc2[dp];

    float gx = fmaf(p.x, c0.x, fmaf(p.y, c1.x, fmaf(p.z, c2.x, fmaf(p.w, c3.x, bA.x))));
    float gy = fmaf(p.x, c0.y, fmaf(p.y, c1.y, fmaf(p.z, c2.y, fmaf(p.w, c3.y, bA.y))));
    float hx = fmaf(p.x, e0.x, fmaf(p.y, e1.x, fmaf(p.z, e2.x, fmaf(p.w, e3.x, bB.x))));
    float hy = fmaf(p.x, e0.y, fmaf(p.y, e1.y, fmaf(p.z, e2.y, fmaf(p.w, e3.y, bB.y))));

    g1[node * 32 + dp] = f2bf(gx) | (f2bf(gy) << 16);
    g2[node * 32 + dp] = f2bf(hx) | (f2bf(hy) << 16);
}

// ---------------- Kernel C: per-edge gather + relu + 2-col head ----------------
// One thread per edge. Gathers two 128B bf16 rows (L2-resident via swizzle),
// relu-add, dot with W2 cols 2,3 (staged in LDS), write float4 output.
#define PAIR(ua, ub, dbase)                                        \
    {                                                              \
        float a0 = __uint_as_float((ua) << 16);                    \
        float a1 = __uint_as_float((ua) & 0xffff0000u);            \
        float b0 = __uint_as_float((ub) << 16);                    \
        float b1v = __uint_as_float((ub) & 0xffff0000u);           \
        float h0 = fmaxf(a0 + b0, 0.f);                            \
        float h1 = fmaxf(a1 + b1v, 0.f);                           \
        float4 w = *((const float4*)&w2s[(dbase) * 2]);            \
        acc2 = fmaf(h0, w.x, acc2);                                \
        acc3 = fmaf(h0, w.y, acc3);                                \
        acc2 = fmaf(h1, w.z, acc2);                                \
        acc3 = fmaf(h1, w.w, acc3);                                \
    }

__global__ __launch_bounds__(256) void edge_kernel(
    const unsigned* __restrict__ g1, const unsigned* __restrict__ g2,
    const int* __restrict__ esrc, const int* __restrict__ edst,
    const float4* __restrict__ line_param, const float* __restrict__ W2,
    const float* __restrict__ b2, float4* __restrict__ out) {
    __shared__ __align__(16) float w2s[128];  // [2d]={W2[d][2]}, [2d+1]={W2[d][3]}
    int tid = threadIdx.x;
    if (tid < 64) {
        ((float2*)w2s)[tid] = make_float2(W2[tid * 4 + 2], W2[tid * 4 + 3]);
    }
    __syncthreads();

    int bid = blockIdx.x;      // 0..4095
    int x = bid & 7;           // XCD
    int i = bid >> 3;          // 0..511
    int b = x + 8 * (i >> 7);  // batch: 4 per XCD (same mapping as node_kernel)
    int chunk = i & 127;
    int e = b * L_ + chunk * 256 + tid;

    int s = esrc[e];
    int t = edst[e];
    const uint4* r1 = (const uint4*)(g1 + ((b * N_ + s) << 5));
    const uint4* r2 = (const uint4*)(g2 + ((b * N_ + t) << 5));

    float acc2 = b2[2], acc3 = b2[3];
#pragma unroll
    for (int c = 0; c < 8; ++c) {
        uint4 a = r1[c];
        uint4 g = r2[c];
        int dbase = c * 8;
        PAIR(a.x, g.x, dbase);
        PAIR(a.y, g.y, dbase + 2);
        PAIR(a.z, g.z, dbase + 4);
        PAIR(a.w, g.w, dbase + 6);
    }

    float4 lp = line_param[e];
    out[e] = make_float4(lp.x, lp.y, acc2, acc3);
}

extern "C" void kernel_launch(void* const* d_in, const int* in_sizes, int n_in,
                              void* d_out, int out_size, void* d_ws, size_t ws_size,
                              hipStream_t stream) {
    const float* pred_node = (const float*)d_in[0];   // (B,N,4)
    const float* line_param = (const float*)d_in[1];  // (B,L,4)
    const float* W_embed = (const float*)d_in[2];     // (4,64)
    const float* b_embed = (const float*)d_in[3];     // (64,)
    const float* W1 = (const float*)d_in[4];          // (128,64)
    const float* b1 = (const float*)d_in[5];          // (64,)
    const float* W2 = (const float*)d_in[6];          // (64,4)
    const float* b2 = (const float*)d_in[7];          // (4,)
    const int* esrc = (const int*)d_in[8];            // (B,L)
    const int* edst = (const int*)d_in[9];            // (B,L)
    float* out = (float*)d_out;                       // (B,L,4)

    float* wc = (float*)d_ws;
    unsigned* g1 = (unsigned*)((char*)d_ws + 4096);
    unsigned* g2 = (unsigned*)((char*)d_ws + 4096 + (size_t)8 * 1024 * 1024);

    prep_kernel<<<1, 64, 0, stream>>>(W_embed, b_embed, W1, b1, wc);
    node_kernel<<<8192, 256, 0, stream>>>((const float4*)pred_node, wc, g1, g2);
    edge_kernel<<<4096, 256, 0, stream>>>(g1, g2, esrc, edst,
                                          (const float4*)line_param, W2, b2,
                                          (float4*)out);
}

// Round 2
// 135.145 us; speedup vs baseline: 1.1257x; 1.1257x over previous
//
#include <hip/hip_runtime.h>
#include <stdint.h>

// Problem constants: B=32, N=2048, L=32768, D_IN=4, D=64
#define B_ 32
#define N_ 2048
#define L_ 32768

// Workspace layout (floats):
//   [0,256)    wc1: (4x64)  W_embed @ W1_top        (row-major, row i = input dim)
//   [256,512)  wc2: (4x64)  W_embed @ W1_bot
//   [512,576)  bc:  (64)    b_embed@W1_top + b_embed@W1_bot + b1   (merged bias)
//   [640,768)  w2p: (128)   w2p[2f]=W2[f][2], w2p[2f+1]=W2[f][3]
// Total < 4 KB.

static __device__ __forceinline__ float4 f4fma(float s, float4 a, float4 b) {
    return make_float4(fmaf(s, a.x, b.x), fmaf(s, a.y, b.y),
                       fmaf(s, a.z, b.z), fmaf(s, a.w, b.w));
}

// ---------------- Kernel A: fold all linears ----------------
__global__ void prep_kernel(const float* __restrict__ W_embed,
                            const float* __restrict__ b_embed,
                            const float* __restrict__ W1,
                            const float* __restrict__ b1,
                            const float* __restrict__ W2,
                            float* __restrict__ wc) {
    int d = threadIdx.x;  // 0..63
    float acc1[4] = {0.f, 0.f, 0.f, 0.f};
    float acc2[4] = {0.f, 0.f, 0.f, 0.f};
    float bb = 0.f;
    for (int k = 0; k < 64; ++k) {
        float w1a = W1[k * 64 + d];          // W1_top column d
        float w1b = W1[(64 + k) * 64 + d];   // W1_bot column d
        float be = b_embed[k];
        bb = fmaf(be, w1a + w1b, bb);
#pragma unroll
        for (int i = 0; i < 4; ++i) {
            float we = W_embed[i * 64 + k];
            acc1[i] = fmaf(we, w1a, acc1[i]);
            acc2[i] = fmaf(we, w1b, acc2[i]);
        }
    }
#pragma unroll
    for (int i = 0; i < 4; ++i) {
        wc[i * 64 + d] = acc1[i];
        wc[256 + i * 64 + d] = acc2[i];
    }
    wc[512 + d] = bb + b1[d];            // merged bias (g1+g2 share one bias)
    wc[640 + 2 * d] = W2[d * 4 + 2];     // head col 2
    wc[641 + 2 * d] = W2[d * 4 + 3];     // head col 3
}

// ---------------- Kernel B: fused per-edge kernel ----------------
// 8 lanes per edge; lane k owns features 8k..8k+7 (weights in VGPRs, loaded
// once per block). Gathers are 16B group-broadcast float4 loads of pred_node
// (32 KB/batch -> L1-resident). 3-level shfl_xor reduce for the 2 head cols.
// Block->batch swizzle: batch b on XCD b%8 keeps pred_node[b] L2/L1-local.
__global__ __launch_bounds__(256) void edge_kernel(
    const float4* __restrict__ pred_node,  // (B*N) float4 rows
    const float* __restrict__ wc,
    const int* __restrict__ esrc, const int* __restrict__ edst,
    const float2* __restrict__ lp2,        // line_param as float2 pairs
    const float* __restrict__ b2,
    float4* __restrict__ out) {
    int tid = threadIdx.x;
    int k = tid & 7;    // feature-chunk lane within edge group
    int g = tid >> 3;   // edge group within block, 0..31

    int bid = blockIdx.x;       // 0..2047
    int x = bid & 7;            // XCD
    int i = bid >> 3;           // 0..255
    int b = x + 8 * (i >> 6);   // batch: 4 batches per XCD
    int j = i & 63;             // block within batch

    // ---- load per-lane weights (once per block) ----
    const float4* wcv = (const float4*)wc;
    float4 c1a[4], c1b[4], c2a[4], c2b[4];
#pragma unroll
    for (int r = 0; r < 4; ++r) {
        c1a[r] = wcv[r * 16 + k * 2];
        c1b[r] = wcv[r * 16 + k * 2 + 1];
        c2a[r] = wcv[64 + r * 16 + k * 2];
        c2b[r] = wcv[64 + r * 16 + k * 2 + 1];
    }
    float4 bc0 = wcv[128 + k * 2];
    float4 bc1 = wcv[128 + k * 2 + 1];
    float4 w20 = wcv[160 + k * 4];
    float4 w21 = wcv[160 + k * 4 + 1];
    float4 w22 = wcv[160 + k * 4 + 2];
    float4 w23 = wcv[160 + k * 4 + 3];
    float bias2 = b2[2], bias3 = b2[3];

    const float4* pn = pred_node + b * N_;
    int ebase = b * L_ + j * 512 + g;

#pragma unroll 2
    for (int p = 0; p < 16; ++p) {
        int e = ebase + p * 32;
        int s = esrc[e];
        int t = edst[e];
        float4 ps = pn[s];   // broadcast within 8-lane group
        float4 pt = pn[t];

        // h[f] = relu( ps@wc1 + pt@wc2 + bc ), features 8k..8k+7
        float4 h0 = bc0, h1 = bc1;
        h0 = f4fma(ps.x, c1a[0], h0); h1 = f4fma(ps.x, c1b[0], h1);
        h0 = f4fma(ps.y, c1a[1], h0); h1 = f4fma(ps.y, c1b[1], h1);
        h0 = f4fma(ps.z, c1a[2], h0); h1 = f4fma(ps.z, c1b[2], h1);
        h0 = f4fma(ps.w, c1a[3], h0); h1 = f4fma(ps.w, c1b[3], h1);
        h0 = f4fma(pt.x, c2a[0], h0); h1 = f4fma(pt.x, c2b[0], h1);
        h0 = f4fma(pt.y, c2a[1], h0); h1 = f4fma(pt.y, c2b[1], h1);
        h0 = f4fma(pt.z, c2a[2], h0); h1 = f4fma(pt.z, c2b[2], h1);
        h0 = f4fma(pt.w, c2a[3], h0); h1 = f4fma(pt.w, c2b[3], h1);
        h0.x = fmaxf(h0.x, 0.f); h0.y = fmaxf(h0.y, 0.f);
        h0.z = fmaxf(h0.z, 0.f); h0.w = fmaxf(h0.w, 0.f);
        h1.x = fmaxf(h1.x, 0.f); h1.y = fmaxf(h1.y, 0.f);
        h1.z = fmaxf(h1.z, 0.f); h1.w = fmaxf(h1.w, 0.f);

        // head: acc2/acc3 partial dot over this lane's 8 features
        float acc2, acc3;
        acc2 = h0.x * w20.x;              acc3 = h0.x * w20.y;
        acc2 = fmaf(h0.y, w20.z, acc2);   acc3 = fmaf(h0.y, w20.w, acc3);
        acc2 = fmaf(h0.z, w21.x, acc2);   acc3 = fmaf(h0.z, w21.y, acc3);
        acc2 = fmaf(h0.w, w21.z, acc2);   acc3 = fmaf(h0.w, w21.w, acc3);
        acc2 = fmaf(h1.x, w22.x, acc2);   acc3 = fmaf(h1.x, w22.y, acc3);
        acc2 = fmaf(h1.y, w22.z, acc2);   acc3 = fmaf(h1.y, w22.w, acc3);
        acc2 = fmaf(h1.z, w23.x, acc2);   acc3 = fmaf(h1.z, w23.y, acc3);
        acc2 = fmaf(h1.w, w23.z, acc2);   acc3 = fmaf(h1.w, w23.w, acc3);

        // reduce across the 8-lane group
        acc2 += __shfl_xor(acc2, 1); acc3 += __shfl_xor(acc3, 1);
        acc2 += __shfl_xor(acc2, 2); acc3 += __shfl_xor(acc3, 2);
        acc2 += __shfl_xor(acc2, 4); acc3 += __shfl_xor(acc3, 4);

        if (k == 0) {
            float2 v = lp2[(size_t)e * 2];  // line_param[e][0:2]
            out[e] = make_float4(v.x, v.y, acc2 + bias2, acc3 + bias3);
        }
    }
}

extern "C" void kernel_launch(void* const* d_in, const int* in_sizes, int n_in,
                              void* d_out, int out_size, void* d_ws, size_t ws_size,
                              hipStream_t stream) {
    const float* pred_node = (const float*)d_in[0];   // (B,N,4)
    const float* line_param = (const float*)d_in[1];  // (B,L,4)
    const float* W_embed = (const float*)d_in[2];     // (4,64)
    const float* b_embed = (const float*)d_in[3];     // (64,)
    const float* W1 = (const float*)d_in[4];          // (128,64)
    const float* b1 = (const float*)d_in[5];          // (64,)
    const float* W2 = (const float*)d_in[6];          // (64,4)
    const float* b2 = (const float*)d_in[7];          // (4,)
    const int* esrc = (const int*)d_in[8];            // (B,L)
    const int* edst = (const int*)d_in[9];            // (B,L)
    float* out = (float*)d_out;                       // (B,L,4)

    float* wc = (float*)d_ws;

    prep_kernel<<<1, 64, 0, stream>>>(W_embed, b_embed, W1, b1, W2, wc);
    edge_kernel<<<2048, 256, 0, stream>>>((const float4*)pred_node, wc,
                                          esrc, edst,
                                          (const float2*)line_param, b2,
                                          (float4*)out);
}

// Round 3
// 128.670 us; speedup vs baseline: 1.1824x; 1.0503x over previous
//
#include <hip/hip_runtime.h>
#include <stdint.h>

// Problem constants: B=32, N=2048, L=32768, D_IN=4, D=64
#define B_ 32
#define N_ 2048
#define L_ 32768

// Workspace layout (floats):
//   [0,256)    wc1: (4x64)  W_embed @ W1_top   (row i = input dim, col = feature)
//   [256,512)  wc2: (4x64)  W_embed @ W1_bot
//   [512,576)  bc:  (64)    b_embed@W1_top + b_embed@W1_bot + b1   (merged bias)
//   [640,768)  w2p: (128)   w2p[2f]=W2[f][2], w2p[2f+1]=W2[f][3]

static __device__ __forceinline__ float4 f4fma(float s, float4 a, float4 b) {
    return make_float4(fmaf(s, a.x, b.x), fmaf(s, a.y, b.y),
                       fmaf(s, a.z, b.z), fmaf(s, a.w, b.w));
}

// ---------------- Kernel A: fold all linears ----------------
__global__ void prep_kernel(const float* __restrict__ W_embed,
                            const float* __restrict__ b_embed,
                            const float* __restrict__ W1,
                            const float* __restrict__ b1,
                            const float* __restrict__ W2,
                            float* __restrict__ wc) {
    int d = threadIdx.x;  // 0..63
    float acc1[4] = {0.f, 0.f, 0.f, 0.f};
    float acc2[4] = {0.f, 0.f, 0.f, 0.f};
    float bb = 0.f;
    for (int k = 0; k < 64; ++k) {
        float w1a = W1[k * 64 + d];          // W1_top column d
        float w1b = W1[(64 + k) * 64 + d];   // W1_bot column d
        float be = b_embed[k];
        bb = fmaf(be, w1a + w1b, bb);
#pragma unroll
        for (int i = 0; i < 4; ++i) {
            float we = W_embed[i * 64 + k];
            acc1[i] = fmaf(we, w1a, acc1[i]);
            acc2[i] = fmaf(we, w1b, acc2[i]);
        }
    }
#pragma unroll
    for (int i = 0; i < 4; ++i) {
        wc[i * 64 + d] = acc1[i];
        wc[256 + i * 64 + d] = acc2[i];
    }
    wc[512 + d] = bb + b1[d];            // merged bias (g1+g2 share one bias)
    wc[640 + 2 * d] = W2[d * 4 + 2];     // head col 2
    wc[641 + 2 * d] = W2[d * 4 + 3];     // head col 3
}

// ---------------- Kernel B: fused per-edge kernel, LDS-staged nodes ----------
// Per block: stage the whole batch's pred_node (2048 x float4 = 32 KB) in LDS,
// then 8 lanes per edge; lane k owns features 8k..8k+7 with the folded weights
// pinned in VGPRs (launch_bounds(256,3) gives the allocator room so they are
// NOT re-loaded in-loop, which was round-2's stall). All 32 edge indices are
// preloaded before the compute loop; the only in-loop latency is ds_read_b128.
__global__ __launch_bounds__(256, 3) void edge_kernel(
    const float4* __restrict__ pred_node,  // (B*N) float4 rows
    const float* __restrict__ wc,
    const int* __restrict__ esrc, const int* __restrict__ edst,
    const float2* __restrict__ lp2,        // line_param as float2 pairs
    const float* __restrict__ b2,
    float4* __restrict__ out) {
    __shared__ float4 spn[N_];  // 32 KB: this batch's pred_node

    int tid = threadIdx.x;
    int k = tid & 7;    // feature-chunk lane within edge group
    int g = tid >> 3;   // edge group within block, 0..31

    int bid = blockIdx.x;       // 0..2047
    int x = bid & 7;            // XCD
    int i = bid >> 3;           // 0..255
    int b = x + 8 * (i >> 6);   // batch: 4 batches per XCD
    int j = i & 63;             // block within batch

    // ---- stage pred_node[b] into LDS (coalesced float4) ----
    const float4* pnb = pred_node + b * N_;
#pragma unroll
    for (int q = 0; q < 8; ++q) {
        int idx = tid + q * 256;
        spn[idx] = pnb[idx];
    }

    // ---- load per-lane weights (once; stay in VGPRs) ----
    const float4* wcv = (const float4*)wc;
    float4 c1a[4], c1b[4], c2a[4], c2b[4];
#pragma unroll
    for (int r = 0; r < 4; ++r) {
        c1a[r] = wcv[r * 16 + k * 2];
        c1b[r] = wcv[r * 16 + k * 2 + 1];
        c2a[r] = wcv[64 + r * 16 + k * 2];
        c2b[r] = wcv[64 + r * 16 + k * 2 + 1];
    }
    float4 bc0 = wcv[128 + k * 2];
    float4 bc1 = wcv[128 + k * 2 + 1];
    float4 w20 = wcv[160 + k * 4];
    float4 w21 = wcv[160 + k * 4 + 1];
    float4 w22 = wcv[160 + k * 4 + 2];
    float4 w23 = wcv[160 + k * 4 + 3];
    float bias2 = b2[2], bias3 = b2[3];

    int ebase = b * L_ + j * 512 + g;

    // ---- preload all 32 edge indices (coalesced, independent loads) ----
    int sarr[16], tarr[16];
#pragma unroll
    for (int p = 0; p < 16; ++p) {
        int e = ebase + p * 32;
        sarr[p] = esrc[e];
        tarr[p] = edst[e];
    }

    __syncthreads();  // staging complete

#pragma unroll
    for (int p = 0; p < 16; ++p) {
        int e = ebase + p * 32;
        float4 ps = spn[sarr[p]];   // ds_read_b128, broadcast within 8-lane group
        float4 pt = spn[tarr[p]];

        // h[f] = relu( ps@wc1 + pt@wc2 + bc ), features 8k..8k+7
        float4 h0 = bc0, h1 = bc1;
        h0 = f4fma(ps.x, c1a[0], h0); h1 = f4fma(ps.x, c1b[0], h1);
        h0 = f4fma(ps.y, c1a[1], h0); h1 = f4fma(ps.y, c1b[1], h1);
        h0 = f4fma(ps.z, c1a[2], h0); h1 = f4fma(ps.z, c1b[2], h1);
        h0 = f4fma(ps.w, c1a[3], h0); h1 = f4fma(ps.w, c1b[3], h1);
        h0 = f4fma(pt.x, c2a[0], h0); h1 = f4fma(pt.x, c2b[0], h1);
        h0 = f4fma(pt.y, c2a[1], h0); h1 = f4fma(pt.y, c2b[1], h1);
        h0 = f4fma(pt.z, c2a[2], h0); h1 = f4fma(pt.z, c2b[2], h1);
        h0 = f4fma(pt.w, c2a[3], h0); h1 = f4fma(pt.w, c2b[3], h1);
        h0.x = fmaxf(h0.x, 0.f); h0.y = fmaxf(h0.y, 0.f);
        h0.z = fmaxf(h0.z, 0.f); h0.w = fmaxf(h0.w, 0.f);
        h1.x = fmaxf(h1.x, 0.f); h1.y = fmaxf(h1.y, 0.f);
        h1.z = fmaxf(h1.z, 0.f); h1.w = fmaxf(h1.w, 0.f);

        // head: acc2/acc3 partial dot over this lane's 8 features
        float acc2, acc3;
        acc2 = h0.x * w20.x;              acc3 = h0.x * w20.y;
        acc2 = fmaf(h0.y, w20.z, acc2);   acc3 = fmaf(h0.y, w20.w, acc3);
        acc2 = fmaf(h0.z, w21.x, acc2);   acc3 = fmaf(h0.z, w21.y, acc3);
        acc2 = fmaf(h0.w, w21.z, acc2);   acc3 = fmaf(h0.w, w21.w, acc3);
        acc2 = fmaf(h1.x, w22.x, acc2);   acc3 = fmaf(h1.x, w22.y, acc3);
        acc2 = fmaf(h1.y, w22.z, acc2);   acc3 = fmaf(h1.y, w22.w, acc3);
        acc2 = fmaf(h1.z, w23.x, acc2);   acc3 = fmaf(h1.z, w23.y, acc3);
        acc2 = fmaf(h1.w, w23.z, acc2);   acc3 = fmaf(h1.w, w23.w, acc3);

        // reduce across the 8-lane group (stays within group: xor 1,2,4)
        acc2 += __shfl_xor(acc2, 1); acc3 += __shfl_xor(acc3, 1);
        acc2 += __shfl_xor(acc2, 2); acc3 += __shfl_xor(acc3, 2);
        acc2 += __shfl_xor(acc2, 4); acc3 += __shfl_xor(acc3, 4);

        if (k == 0) {
            float2 v = lp2[(size_t)e * 2];  // line_param[e][0:2]
            out[e] = make_float4(v.x, v.y, acc2 + bias2, acc3 + bias3);
        }
    }
}

extern "C" void kernel_launch(void* const* d_in, const int* in_sizes, int n_in,
                              void* d_out, int out_size, void* d_ws, size_t ws_size,
                              hipStream_t stream) {
    const float* pred_node = (const float*)d_in[0];   // (B,N,4)
    const float* line_param = (const float*)d_in[1];  // (B,L,4)
    const float* W_embed = (const float*)d_in[2];     // (4,64)
    const float* b_embed = (const float*)d_in[3];     // (64,)
    const float* W1 = (const float*)d_in[4];          // (128,64)
    const float* b1 = (const float*)d_in[5];          // (64,)
    const float* W2 = (const float*)d_in[6];          // (64,4)
    const float* b2 = (const float*)d_in[7];          // (4,)
    const int* esrc = (const int*)d_in[8];            // (B,L)
    const int* edst = (const int*)d_in[9];            // (B,L)
    float* out = (float*)d_out;                       // (B,L,4)

    float* wc = (float*)d_ws;

    prep_kernel<<<1, 64, 0, stream>>>(W_embed, b_embed, W1, b1, W2, wc);
    edge_kernel<<<2048, 256, 0, stream>>>((const float4*)pred_node, wc,
                                          esrc, edst,
                                          (const float2*)line_param, b2,
                                          (float4*)out);
}

// Round 4
// 115.456 us; speedup vs baseline: 1.3177x; 1.1144x over previous
//
#include <hip/hip_runtime.h>
#include <stdint.h>

// Problem constants: B=32, N=2048, L=32768, D_IN=4, D=64
#define B_ 32
#define N_ 2048
#define L_ 32768

// Workspace layout (floats), written by prep_kernel:
//   wc[f*12 + 0..3]  = (W_embed @ W1_top) column f   (coeffs for src node ps)
//   wc[f*12 + 4..7]  = (W_embed @ W1_bot) column f   (coeffs for dst node pt)
//   wc[f*12 + 8]     = merged bias: (b_embed@W1_top + b_embed@W1_bot + b1)[f]
//   wc[f*12 + 9]     = W2[f][2]
//   wc[f*12 + 10]    = W2[f][3]
//   wc[f*12 + 11]    = pad (keeps each feature's 12 floats 16B-aligned)
// 64*12*4 = 3072 B.

// ---------------- Kernel A: fold all linears ----------------
__global__ void prep_kernel(const float* __restrict__ W_embed,
                            const float* __restrict__ b_embed,
                            const float* __restrict__ W1,
                            const float* __restrict__ b1,
                            const float* __restrict__ W2,
                            float* __restrict__ wc) {
    int d = threadIdx.x;  // 0..63 = feature f
    float acc1[4] = {0.f, 0.f, 0.f, 0.f};
    float acc2[4] = {0.f, 0.f, 0.f, 0.f};
    float bb = 0.f;
    for (int k = 0; k < 64; ++k) {
        float w1a = W1[k * 64 + d];          // W1_top column d
        float w1b = W1[(64 + k) * 64 + d];   // W1_bot column d
        float be = b_embed[k];
        bb = fmaf(be, w1a + w1b, bb);
#pragma unroll
        for (int i = 0; i < 4; ++i) {
            float we = W_embed[i * 64 + k];
            acc1[i] = fmaf(we, w1a, acc1[i]);
            acc2[i] = fmaf(we, w1b, acc2[i]);
        }
    }
    float* w = wc + d * 12;
#pragma unroll
    for (int i = 0; i < 4; ++i) {
        w[i] = acc1[i];
        w[4 + i] = acc2[i];
    }
    w[8] = bb + b1[d];
    w[9] = W2[d * 4 + 2];
    w[10] = W2[d * 4 + 3];
    w[11] = 0.f;
}

// ---------------- Kernel B: one-thread-per-edge, scalar-pipe weights --------
// Each thread owns 4 edges. Nodes for the block's batch staged in LDS (32 KB).
// Weights are wave-uniform -> compiler streams them through SGPRs (s_load),
// costing no VGPRs and no LDS traffic; each v_fma takes the weight as its one
// legal SGPR operand. h is consumed into acc2/acc3 immediately (no h[64]
// array), so there is no cross-lane reduce and no divergent store.
// Grid: 1024 blocks = 4/CU, all resident under __launch_bounds__(256,4).
__global__ __launch_bounds__(256, 4) void edge_kernel(
    const float4* __restrict__ pred_node,  // (B*N) float4 rows
    const float* __restrict__ wc,
    const int* __restrict__ esrc, const int* __restrict__ edst,
    const float2* __restrict__ lp2,        // line_param as float2 pairs
    const float* __restrict__ b2,
    float4* __restrict__ out) {
    __shared__ float4 spn[N_];  // 32 KB: this batch's pred_node

    int tid = threadIdx.x;
    int bid = blockIdx.x;       // 0..1023
    int x = bid & 7;            // XCD (dispatch round-robin heuristic)
    int i = bid >> 3;           // 0..127
    int b = x + 8 * (i >> 5);   // batch: 4 batches per XCD
    int j = i & 31;             // block within batch (32 blocks x 1024 edges)

    // ---- stage pred_node[b] into LDS (coalesced float4) ----
    const float4* pnb = pred_node + b * N_;
#pragma unroll
    for (int q = 0; q < 8; ++q) {
        int idx = tid + q * 256;
        spn[idx] = pnb[idx];
    }

    int ebase = b * L_ + j * 1024 + tid;

    // ---- preload this thread's 4 edge index pairs (coalesced) ----
    int sa[4], ta[4];
#pragma unroll
    for (int p = 0; p < 4; ++p) {
        sa[p] = esrc[ebase + p * 256];
        ta[p] = edst[ebase + p * 256];
    }
    float bias2 = b2[2], bias3 = b2[3];  // uniform -> s_load

    __syncthreads();  // staging complete

    // ---- gather 4 edge node-pairs from LDS ----
    float4 ps[4], pt[4];
#pragma unroll
    for (int p = 0; p < 4; ++p) {
        ps[p] = spn[sa[p]];
        pt[p] = spn[ta[p]];
    }

    float a2[4] = {bias2, bias2, bias2, bias2};
    float a3[4] = {bias3, bias3, bias3, bias3};

    const float4* wq = (const float4*)wc;  // 3 float4 per feature
#pragma unroll 1
    for (int fc = 0; fc < 16; ++fc) {  // 4 features per chunk; weights in SGPRs
#pragma unroll
        for (int f = 0; f < 4; ++f) {
            int fi = fc * 4 + f;
            float4 wa = wq[fi * 3 + 0];  // src coeffs  (uniform -> SGPR)
            float4 wb = wq[fi * 3 + 1];  // dst coeffs
            float4 wx = wq[fi * 3 + 2];  // {bias, w2c2, w2c3, pad}
#pragma unroll
            for (int p = 0; p < 4; ++p) {
                float h = wx.x;
                h = fmaf(ps[p].x, wa.x, h);
                h = fmaf(ps[p].y, wa.y, h);
                h = fmaf(ps[p].z, wa.z, h);
                h = fmaf(ps[p].w, wa.w, h);
                h = fmaf(pt[p].x, wb.x, h);
                h = fmaf(pt[p].y, wb.y, h);
                h = fmaf(pt[p].z, wb.z, h);
                h = fmaf(pt[p].w, wb.w, h);
                h = fmaxf(h, 0.f);
                a2[p] = fmaf(h, wx.y, a2[p]);
                a3[p] = fmaf(h, wx.z, a3[p]);
            }
        }
    }

#pragma unroll
    for (int p = 0; p < 4; ++p) {
        int e = ebase + p * 256;
        float2 v = lp2[(size_t)e * 2];  // line_param[e][0:2]
        out[e] = make_float4(v.x, v.y, a2[p], a3[p]);
    }
}

extern "C" void kernel_launch(void* const* d_in, const int* in_sizes, int n_in,
                              void* d_out, int out_size, void* d_ws, size_t ws_size,
                              hipStream_t stream) {
    const float* pred_node = (const float*)d_in[0];   // (B,N,4)
    const float* line_param = (const float*)d_in[1];  // (B,L,4)
    const float* W_embed = (const float*)d_in[2];     // (4,64)
    const float* b_embed = (const float*)d_in[3];     // (64,)
    const float* W1 = (const float*)d_in[4];          // (128,64)
    const float* b1 = (const float*)d_in[5];          // (64,)
    const float* W2 = (const float*)d_in[6];          // (64,4)
    const float* b2 = (const float*)d_in[7];          // (4,)
    const int* esrc = (const int*)d_in[8];            // (B,L)
    const int* edst = (const int*)d_in[9];            // (B,L)
    float* out = (float*)d_out;                       // (B,L,4)

    float* wc = (float*)d_ws;

    prep_kernel<<<1, 64, 0, stream>>>(W_embed, b_embed, W1, b1, W2, wc);
    edge_kernel<<<1024, 256, 0, stream>>>((const float4*)pred_node, wc,
                                          esrc, edst,
                                          (const float2*)line_param, b2,
                                          (float4*)out);
}

// Round 5
// 115.199 us; speedup vs baseline: 1.3206x; 1.0022x over previous
//
#include <hip/hip_runtime.h>
#include <stdint.h>

// Problem constants: B=32, N=2048, L=32768, D_IN=4, D=64
#define B_ 32
#define N_ 2048
#define L_ 32768

// Workspace layout (floats), written by prep_kernel:
//   wc[f*12 + 0..3]  = (W_embed @ W1_top) column f   (coeffs for src node ps)
//   wc[f*12 + 4..7]  = (W_embed @ W1_bot) column f   (coeffs for dst node pt)
//   wc[f*12 + 8]     = merged bias: (b_embed@W1_top + b_embed@W1_bot + b1)[f]
//   wc[f*12 + 9]     = W2[f][2]
//   wc[f*12 + 10]    = W2[f][3]
//   wc[f*12 + 11]    = pad (keeps each feature's 12 floats 16B-aligned)
// 64*12*4 = 3072 B.

// ---------------- Kernel A: fold all linears (parallel: 8 waves) ------------
// Round-4's prep was a single-wave kernel with ~400 global loads -> ~10us of
// serial dead time. Now: 512 threads; wave w handles (half = w>>2, i = w&3),
// lane d = feature column. Each thread does one dot-64 with coalesced W1
// column loads. No barriers needed (threads independent).
__global__ __launch_bounds__(512) void prep_kernel(
    const float* __restrict__ W_embed, const float* __restrict__ b_embed,
    const float* __restrict__ W1, const float* __restrict__ b1,
    const float* __restrict__ W2, float* __restrict__ wc) {
    int tid = threadIdx.x;
    int d = tid & 63;          // feature column (lane)
    int i = (tid >> 6) & 3;    // input dim (wave-uniform)
    int half = tid >> 8;       // 0 = top (src), 1 = bot (dst)

    const float* w1base = W1 + (half ? 64 * 64 : 0);
    float acc = 0.f;
#pragma unroll
    for (int k = 0; k < 64; ++k) {
        acc = fmaf(W_embed[i * 64 + k], w1base[k * 64 + d], acc);
    }
    wc[d * 12 + half * 4 + i] = acc;

    if (tid < 64) {  // merged bias + head cols (W1 cols are L1-hot by now)
        float bb = 0.f;
#pragma unroll
        for (int k = 0; k < 64; ++k) {
            bb = fmaf(b_embed[k], W1[k * 64 + d] + W1[(64 + k) * 64 + d], bb);
        }
        wc[d * 12 + 8] = bb + b1[d];
        wc[d * 12 + 9] = W2[d * 4 + 2];
        wc[d * 12 + 10] = W2[d * 4 + 3];
        wc[d * 12 + 11] = 0.f;
    }
}

// ---------------- Kernel B: one-thread-per-edge, scalar-pipe weights --------
// 8 edges per thread (vs 4 in round 4): each 192B s_load weight chunk now
// covers 704 VALU cycles instead of 352, and `unroll 2` on the chunk loop
// lets the scheduler hoist chunk fc+1's s_loads over chunk fc's compute
// (round 4's unroll-1 exposed lgkmcnt latency at every chunk head).
// Nodes staged in LDS; lp2 operands prefetched before the compute loop.
// Grid: 512 blocks x 256 thr = 2 blocks/CU (64KB LDS), 8 waves/CU.
__global__ __launch_bounds__(256, 2) void edge_kernel(
    const float4* __restrict__ pred_node,  // (B*N) float4 rows
    const float* __restrict__ wc,
    const int* __restrict__ esrc, const int* __restrict__ edst,
    const float2* __restrict__ lp2,        // line_param as float2 pairs
    const float* __restrict__ b2,
    float4* __restrict__ out) {
    __shared__ float4 spn[N_];  // 32 KB: this batch's pred_node

    int tid = threadIdx.x;
    int bid = blockIdx.x;       // 0..511
    int x = bid & 7;            // XCD (dispatch round-robin heuristic)
    int i = bid >> 3;           // 0..63
    int b = x + 8 * (i >> 4);   // batch: 4 batches per XCD
    int j = i & 15;             // block within batch (16 blocks x 2048 edges)

    // ---- stage pred_node[b] into LDS (coalesced float4) ----
    const float4* pnb = pred_node + b * N_;
#pragma unroll
    for (int q = 0; q < 8; ++q) {
        int idx = tid + q * 256;
        spn[idx] = pnb[idx];
    }

    int ebase = b * L_ + j * 2048 + tid;

    // ---- preload this thread's 8 edge index pairs + lp operands ----
    int sa[8], ta[8];
    float2 lp[8];
#pragma unroll
    for (int p = 0; p < 8; ++p) {
        int e = ebase + p * 256;
        sa[p] = esrc[e];
        ta[p] = edst[e];
        lp[p] = lp2[(size_t)e * 2];  // line_param[e][0:2]
    }
    float bias2 = b2[2], bias3 = b2[3];  // uniform -> s_load

    __syncthreads();  // staging complete

    // ---- gather 8 edge node-pairs from LDS ----
    float4 ps[8], pt[8];
#pragma unroll
    for (int p = 0; p < 8; ++p) {
        ps[p] = spn[sa[p]];
        pt[p] = spn[ta[p]];
    }

    float a2[8], a3[8];
#pragma unroll
    for (int p = 0; p < 8; ++p) { a2[p] = bias2; a3[p] = bias3; }

    const float4* wq = (const float4*)wc;  // 3 float4 per feature
#pragma unroll 2
    for (int fc = 0; fc < 16; ++fc) {  // 4 features per chunk; weights in SGPRs
#pragma unroll
        for (int f = 0; f < 4; ++f) {
            int fi = fc * 4 + f;
            float4 wa = wq[fi * 3 + 0];  // src coeffs  (uniform -> SGPR)
            float4 wb = wq[fi * 3 + 1];  // dst coeffs
            float4 wx = wq[fi * 3 + 2];  // {bias, w2c2, w2c3, pad}
#pragma unroll
            for (int p = 0; p < 8; ++p) {
                float h = wx.x;
                h = fmaf(ps[p].x, wa.x, h);
                h = fmaf(ps[p].y, wa.y, h);
                h = fmaf(ps[p].z, wa.z, h);
                h = fmaf(ps[p].w, wa.w, h);
                h = fmaf(pt[p].x, wb.x, h);
                h = fmaf(pt[p].y, wb.y, h);
                h = fmaf(pt[p].z, wb.z, h);
                h = fmaf(pt[p].w, wb.w, h);
                h = fmaxf(h, 0.f);
                a2[p] = fmaf(h, wx.y, a2[p]);
                a3[p] = fmaf(h, wx.z, a3[p]);
            }
        }
    }

#pragma unroll
    for (int p = 0; p < 8; ++p) {
        int e = ebase + p * 256;
        out[e] = make_float4(lp[p].x, lp[p].y, a2[p], a3[p]);
    }
}

extern "C" void kernel_launch(void* const* d_in, const int* in_sizes, int n_in,
                              void* d_out, int out_size, void* d_ws, size_t ws_size,
                              hipStream_t stream) {
    const float* pred_node = (const float*)d_in[0];   // (B,N,4)
    const float* line_param = (const float*)d_in[1];  // (B,L,4)
    const float* W_embed = (const float*)d_in[2];     // (4,64)
    const float* b_embed = (const float*)d_in[3];     // (64,)
    const float* W1 = (const float*)d_in[4];          // (128,64)
    const float* b1 = (const float*)d_in[5];          // (64,)
    const float* W2 = (const float*)d_in[6];          // (64,4)
    const float* b2 = (const float*)d_in[7];          // (4,)
    const int* esrc = (const int*)d_in[8];            // (B,L)
    const int* edst = (const int*)d_in[9];            // (B,L)
    float* out = (float*)d_out;                       // (B,L,4)

    float* wc = (float*)d_ws;

    prep_kernel<<<1, 512, 0, stream>>>(W_embed, b_embed, W1, b1, W2, wc);
    edge_kernel<<<512, 256, 0, stream>>>((const float4*)pred_node, wc,
                                         esrc, edst,
                                         (const float2*)line_param, b2,
                                         (float4*)out);
}

// Round 7
// 113.795 us; speedup vs baseline: 1.3369x; 1.0123x over previous
//
#include <hip/hip_runtime.h>
#include <hip/hip_fp16.h>
#include <stdint.h>

// Problem constants: B=32, N=2048, L=32768, D_IN=4, D=64
#define B_ 32
#define N_ 2048
#define L_ 32768

// Workspace: packed half2 weight table, 32 feature-pairs x 12 half2 (48 B):
//   [fp*12 + 0..3] : {wc1[i][2fp], wc1[i][2fp+1]} for input dim i of src node
//   [fp*12 + 4..7] : same for dst node (wc2)
//   [fp*12 + 8]    : merged bias pair
//   [fp*12 + 9]    : {W2[2fp][2], W2[2fp+1][2]}
//   [fp*12 + 10]   : {W2[2fp][3], W2[2fp+1][3]}
//   [fp*12 + 11]   : pad
// wc1 = W_embed@W1_top, wc2 = W_embed@W1_bot, bias = (b_embed@(W1_top+W1_bot)+b1).

// ---------------- Kernel A: fold linears, emit packed half2 table -----------
__global__ __launch_bounds__(512) void prep_kernel(
    const float* __restrict__ W_embed, const float* __restrict__ b_embed,
    const float* __restrict__ W1, const float* __restrict__ b1,
    const float* __restrict__ W2, __half2* __restrict__ wh) {
    __shared__ float sacc[64][12];
    int tid = threadIdx.x;
    int d = tid & 63;          // feature column (lane)
    int i = (tid >> 6) & 3;    // input dim (wave-uniform)
    int half = tid >> 8;       // 0 = top (src), 1 = bot (dst)

    const float* w1base = W1 + (half ? 64 * 64 : 0);
    float acc = 0.f;
#pragma unroll
    for (int k = 0; k < 64; ++k) {
        acc = fmaf(W_embed[i * 64 + k], w1base[k * 64 + d], acc);
    }
    sacc[d][half * 4 + i] = acc;

    if (tid < 64) {  // merged bias + head cols
        float bb = 0.f;
#pragma unroll
        for (int k = 0; k < 64; ++k) {
            bb = fmaf(b_embed[k], W1[k * 64 + d] + W1[(64 + k) * 64 + d], bb);
        }
        sacc[d][8] = bb + b1[d];
        sacc[d][9] = W2[d * 4 + 2];
        sacc[d][10] = W2[d * 4 + 3];
    }
    __syncthreads();

    if (tid < 32) {  // pack feature-pair fp = tid
        int f0 = tid * 2, f1 = tid * 2 + 1;
#pragma unroll
        for (int k = 0; k < 11; ++k) {
            wh[tid * 12 + k] = __float22half2_rn(make_float2(sacc[f0][k], sacc[f1][k]));
        }
        wh[tid * 12 + 11] = __float22half2_rn(make_float2(0.f, 0.f));
    }
}

// ---------------- Kernel B: per-edge, packed-fp16 compute -------------------
// 8 edges/thread; nodes staged in LDS (fp32); per edge the 8 node scalars are
// broadcast-packed to half2 once (v_cvt_pkrtz). The 64-feature MLP is then 32
// feature-pairs x 12 v_pk_* instrs (2 MACs/instr) ~ half round-5's VALU count.
// relu is h * (h>0) via __hgt2 (ROCm 7.2 has no __hmax2(__half2,__half2)).
// Weights stay wave-uniform -> scalar loads. a2/a3 accumulate as half2 pairs.
__global__ __launch_bounds__(256, 2) void edge_kernel(
    const float4* __restrict__ pred_node,  // (B*N) float4 rows
    const __half2* __restrict__ wh,
    const int* __restrict__ esrc, const int* __restrict__ edst,
    const float2* __restrict__ lp2,        // line_param as float2 pairs
    const float* __restrict__ b2,
    float4* __restrict__ out) {
    __shared__ float4 spn[N_];  // 32 KB: this batch's pred_node

    int tid = threadIdx.x;
    int bid = blockIdx.x;       // 0..511
    int x = bid & 7;            // XCD (dispatch round-robin heuristic)
    int i = bid >> 3;           // 0..63
    int b = x + 8 * (i >> 4);   // batch: 4 batches per XCD
    int j = i & 15;             // block within batch (16 blocks x 2048 edges)

    // ---- stage pred_node[b] into LDS (coalesced float4) ----
    const float4* pnb = pred_node + b * N_;
#pragma unroll
    for (int q = 0; q < 8; ++q) {
        int idx = tid + q * 256;
        spn[idx] = pnb[idx];
    }

    int ebase = b * L_ + j * 2048 + tid;

    // ---- preload this thread's 8 edge index pairs + lp operands ----
    int sa[8], ta[8];
    float2 lp[8];
#pragma unroll
    for (int p = 0; p < 8; ++p) {
        int e = ebase + p * 256;
        sa[p] = esrc[e];
        ta[p] = edst[e];
        lp[p] = lp2[(size_t)e * 2];  // line_param[e][0:2]
    }
    float bias2 = b2[2], bias3 = b2[3];  // uniform -> s_load

    __syncthreads();  // staging complete

    // ---- gather 8 node-pairs; broadcast-pack each scalar to half2 ----
    __half2 pb[8][8];
#pragma unroll
    for (int p = 0; p < 8; ++p) {
        float4 vs = spn[sa[p]];
        float4 vt = spn[ta[p]];
        pb[p][0] = __float22half2_rn(make_float2(vs.x, vs.x));
        pb[p][1] = __float22half2_rn(make_float2(vs.y, vs.y));
        pb[p][2] = __float22half2_rn(make_float2(vs.z, vs.z));
        pb[p][3] = __float22half2_rn(make_float2(vs.w, vs.w));
        pb[p][4] = __float22half2_rn(make_float2(vt.x, vt.x));
        pb[p][5] = __float22half2_rn(make_float2(vt.y, vt.y));
        pb[p][6] = __float22half2_rn(make_float2(vt.z, vt.z));
        pb[p][7] = __float22half2_rn(make_float2(vt.w, vt.w));
    }

    const __half2 zero = __float22half2_rn(make_float2(0.f, 0.f));
    __half2 acc2[8], acc3[8];
#pragma unroll
    for (int p = 0; p < 8; ++p) { acc2[p] = zero; acc3[p] = zero; }

#pragma unroll 2
    for (int c = 0; c < 8; ++c) {  // 4 feature-pairs per chunk
#pragma unroll
        for (int f = 0; f < 4; ++f) {
            int base = (c * 4 + f) * 12;
            __half2 a0 = wh[base + 0], a1 = wh[base + 1];
            __half2 a2w = wh[base + 2], a3w = wh[base + 3];
            __half2 b0 = wh[base + 4], b1w = wh[base + 5];
            __half2 b2w = wh[base + 6], b3w = wh[base + 7];
            __half2 bs = wh[base + 8];
            __half2 c2 = wh[base + 9], c3 = wh[base + 10];
#pragma unroll
            for (int p = 0; p < 8; ++p) {
                __half2 h = bs;
                h = __hfma2(pb[p][0], a0, h);
                h = __hfma2(pb[p][1], a1, h);
                h = __hfma2(pb[p][2], a2w, h);
                h = __hfma2(pb[p][3], a3w, h);
                h = __hfma2(pb[p][4], b0, h);
                h = __hfma2(pb[p][5], b1w, h);
                h = __hfma2(pb[p][6], b2w, h);
                h = __hfma2(pb[p][7], b3w, h);
                h = __hmul2(h, __hgt2(h, zero));  // relu: h * (h>0)
                acc2[p] = __hfma2(h, c2, acc2[p]);
                acc3[p] = __hfma2(h, c3, acc3[p]);
            }
        }
    }

#pragma unroll
    for (int p = 0; p < 8; ++p) {
        int e = ebase + p * 256;
        float r2 = bias2 + __low2float(acc2[p]) + __high2float(acc2[p]);
        float r3 = bias3 + __low2float(acc3[p]) + __high2float(acc3[p]);
        out[e] = make_float4(lp[p].x, lp[p].y, r2, r3);
    }
}

extern "C" void kernel_launch(void* const* d_in, const int* in_sizes, int n_in,
                              void* d_out, int out_size, void* d_ws, size_t ws_size,
                              hipStream_t stream) {
    const float* pred_node = (const float*)d_in[0];   // (B,N,4)
    const float* line_param = (const float*)d_in[1];  // (B,L,4)
    const float* W_embed = (const float*)d_in[2];     // (4,64)
    const float* b_embed = (const float*)d_in[3];     // (64,)
    const float* W1 = (const float*)d_in[4];          // (128,64)
    const float* b1 = (const float*)d_in[5];          // (64,)
    const float* W2 = (const float*)d_in[6];          // (64,4)
    const float* b2 = (const float*)d_in[7];          // (4,)
    const int* esrc = (const int*)d_in[8];            // (B,L)
    const int* edst = (const int*)d_in[9];            // (B,L)
    float* out = (float*)d_out;                       // (B,L,4)

    __half2* wh = (__half2*)d_ws;

    prep_kernel<<<1, 512, 0, stream>>>(W_embed, b_embed, W1, b1, W2, wh);
    edge_kernel<<<512, 256, 0, stream>>>((const float4*)pred_node, wh,
                                         esrc, edst,
                                         (const float2*)line_param, b2,
                                         (float4*)out);
}